// Round 6
// baseline (251.826 us; speedup 1.0000x reference)
//
#include <hip/hip_runtime.h>

// LSTM: B=4096, T=2048, F=1, H=3. Output h_T [4096,3] fp32.
//
// Fitted cost model (R2/R3/R5, all within 2%): per-wave issue = 2 cyc per
// full-rate VALU + 16 cyc per transcendental (trans unit is 4-wide:
// 64/4=16). R5 16-lane: 105 issue vs 222 wall -> 117 cyc exposed dep
// latency (whole substep is one serial chain; lone wave can't fill gaps).
// R6: 8 lanes/element. Element = 2 quads: Q0 computes i (eval1) + g
// (eval2), Q1 computes f (eval1) + o (eval2) -> TWO INDEPENDENT activation
// evaluations in the stream fill each other's stall slots. eval1 is
// sigmoid on both quads -> v1 = rcp(1+exp2(a)) with no affine fma.
// Gather f,o to Q0: 2x row_shl:4 (parallel). Distribute h: 1 masked
// row_shr:4 + 3 quad_perm. Scale folding exact (cs = -2log2e*c).
// Issue ~= 22F+6T = 140 cyc/step, chain ~= 116 -> wall ~150-170 (vs 222).

#define T_LEN 2048
#define BATCH 4096

template <int CTRL, int RMASK, int BMASK, bool BC>
__device__ __forceinline__ float dppf(float oldv, float src) {
    int r = __builtin_amdgcn_update_dpp(__float_as_int(oldv), __float_as_int(src),
                                        CTRL, RMASK, BMASK, BC);
    return __int_as_float(r);
}

__global__ __launch_bounds__(64, 1) void lstm_kernel(
    const float* __restrict__ X,
    const float* __restrict__ Wih,   // [12,1]
    const float* __restrict__ Whh,   // [12,3]
    const float* __restrict__ bih,   // [12]
    const float* __restrict__ bhh,   // [12]
    float* __restrict__ out)         // [4096,3]
{
    const int lane = threadIdx.x;        // block = 1 wave of 64
    const int l8   = lane & 7;           // lane within element
    const int q    = l8 >> 2;            // 0: quad {i,g}, 1: quad {f,o}
    const int u3   = l8 & 3;
    const int u    = (u3 < 3) ? u3 : 2;  // hidden unit; slot 3 duplicates 2
    const int e    = blockIdx.x * 8 + (lane >> 3);

    // torch gate rows: i 0-2, f 3-5, g 6-8, o 9-11
    const int g1 = (q ? 3 : 0) + u;      // eval1: i (Q0) / f (Q1) -> sigmoid
    const int g2 = (q ? 9 : 6) + u;      // eval2: g (Q0) / o (Q1)

    const float L2E = 1.44269504088896340736f;
    // Scale folding (exact): sigmoid lanes a' = -log2e*A; g lane a' = -2log2e*A
    // and emits gs = -2log2e*tanh(A); cell kept scaled: cs = -2log2e*c.
    const float SC1 = -L2E;
    const float SC2 = q ? -L2E : -2.0f * L2E;

    const float wx1 = Wih[g1] * SC1;
    const float bb1 = (bih[g1] + bhh[g1]) * SC1;
    const float w10 = Whh[g1 * 3 + 0] * SC1;
    const float w11 = Whh[g1 * 3 + 1] * SC1;
    const float w12 = Whh[g1 * 3 + 2] * SC1;

    const float wx2 = Wih[g2] * SC2;
    const float bb2 = (bih[g2] + bhh[g2]) * SC2;
    const float w20 = Whh[g2 * 3 + 0] * SC2;
    const float w21 = Whh[g2 * 3 + 1] * SC2;
    const float w22 = Whh[g2 * 3 + 2] * SC2;

    // eval2 affine: Q1 (o, sigmoid): v = r;  Q0 (g): v = -4log2e*r + 2log2e
    const float am2 = q ? 1.0f : -4.0f * L2E;
    const float ad2 = q ? 0.0f :  2.0f * L2E;

    // All 8 lanes of an element load the same float4 (HW broadcast).
    const float4* xp = (const float4*)(X + (size_t)e * T_LEN);
    constexpr int T8 = T_LEN / 8;

    float4 a0 = xp[0], a1 = xp[1];
    float4 b0 = xp[2], b1 = xp[3];
    float4 c0 = xp[4], c1 = xp[5];

    float h = 0.f, cs = 0.f;             // cs = -2log2e * c
    float h0 = 0.f, h1 = 0.f, h2 = 0.f;

    for (int t8 = 0; t8 < T8; ++t8) {
        int nidx = 2 * t8 + 6;
        nidx = nidx < 2 * T8 - 2 ? nidx : 2 * T8 - 2;
        float4 n0 = xp[nidx];
        float4 n1 = xp[nidx + 1];

        float xs[8] = {a0.x, a0.y, a0.z, a0.w, a1.x, a1.y, a1.z, a1.w};

#pragma unroll
        for (int s = 0; s < 8; ++s) {
            const float x = xs[s];
            float xa1 = __builtin_fmaf(x, wx1, bb1);
            float xa2 = __builtin_fmaf(x, wx2, bb2);

            // two independent preactivation chains (fill each other's stalls)
            float p1 = __builtin_fmaf(h0, w10, xa1);
            float p2 = __builtin_fmaf(h0, w20, xa2);
            p1 = __builtin_fmaf(h1, w11, p1);
            p2 = __builtin_fmaf(h1, w21, p2);
            p1 = __builtin_fmaf(h2, w12, p1);
            p2 = __builtin_fmaf(h2, w22, p2);

            // eval1: sigmoid (i on Q0, f on Q1) -> v1 = rcp(1+exp2(p1))
            float e1 = __builtin_amdgcn_exp2f(p1);
            float v1 = __builtin_amdgcn_rcpf(1.0f + e1);
            // eval2: gs on Q0, o on Q1
            float e2 = __builtin_amdgcn_exp2f(p2);
            float r2 = __builtin_amdgcn_rcpf(1.0f + e2);
            float v2 = __builtin_fmaf(am2, r2, ad2);

            // bring f,o from Q1 to Q0 (parallel DPPs)
            float vf = dppf<0x104, 0xF, 0xF, true>(0.f, v1);  // row_shl:4
            float vo = dppf<0x104, 0xF, 0xF, true>(0.f, v2);  // row_shl:4

            // scaled cell update (valid on Q0)
            cs = __builtin_fmaf(vf, cs, v1 * v2);

            // tanh(c) = fma(2, rcp(1+exp2(cs)), -1)
            float eT = __builtin_amdgcn_exp2f(cs);
            float rT = __builtin_amdgcn_rcpf(1.0f + eT);
            float T  = __builtin_fmaf(2.0f, rT, -1.0f);
            h = vo * T;                                       // valid Q0 lanes 0-2

            // replicate Q0 -> Q1 (banks 1,3 <- banks 0,2), then quad bcast
            h  = dppf<0x114, 0xF, 0xA, false>(h, h);          // row_shr:4
            h0 = dppf<0x00, 0xF, 0xF, true>(0.f, h);
            h1 = dppf<0x55, 0xF, 0xF, true>(0.f, h);
            h2 = dppf<0xAA, 0xF, 0xF, true>(0.f, h);
        }
        a0 = b0; a1 = b1;
        b0 = c0; b1 = c1;
        c0 = n0; c1 = n1;
    }

    if (l8 < 3) out[(size_t)e * 3 + l8] = h;
}

extern "C" void kernel_launch(void* const* d_in, const int* in_sizes, int n_in,
                              void* d_out, int out_size, void* d_ws, size_t ws_size,
                              hipStream_t stream) {
    const float* X   = (const float*)d_in[0];
    const float* Wih = (const float*)d_in[1];
    const float* Whh = (const float*)d_in[2];
    const float* bih = (const float*)d_in[3];
    const float* bhh = (const float*)d_in[4];
    float* out = (float*)d_out;

    // 4096 elements x 8 lanes = 32768 threads = 512 waves (512 of 1024
    // SIMDs, but each wave's stream now has 2-way ILP).
    dim3 grid(BATCH / 8);
    dim3 block(64);
    lstm_kernel<<<grid, block, 0, stream>>>(X, Wih, Whh, bih, bhh, out);
}